// Round 15
// baseline (353.139 us; speedup 1.0000x reference)
//
#include <hip/hip_runtime.h>
#include <hip/hip_bf16.h>

#define DIN 256
#define DH  1024
#define DF  512
#define NROWS 65536

// workspace layout (bytes)
#define WS_WTS   0
#define WS_U     4718592
#define WS_CNT   5242880
#define WS_OFFS  5243904

typedef __attribute__((ext_vector_type(8))) short bf16x8;
typedef __attribute__((ext_vector_type(4))) float f32x4;

__device__ __forceinline__ unsigned short f2b(float f) {
    union { float f; unsigned u; } v; v.f = f;
    unsigned r = v.u + 0x7FFFu + ((v.u >> 16) & 1u);
    return (unsigned short)(r >> 16);
}

__device__ __forceinline__ void gll16(const void* g, void* l) {
    __builtin_amdgcn_global_load_lds(
        (const __attribute__((address_space(1))) void*)g,
        (__attribute__((address_space(3))) void*)l, 16, 0, 0);
}

// counted waits: loop VMEM stream is EXACTLY the 12 gll16/thread per chunk,
// so vmcnt counts are provable (tables/prologue loads force-drained first).
#define BAR_V(N) asm volatile("s_waitcnt vmcnt(" #N ") lgkmcnt(0)\ns_barrier" ::: "memory")
#define DRAIN_VM() asm volatile("s_waitcnt vmcnt(0)" ::: "memory")

// dst[n][k] = (bf16) src[k][n] ; src is K x N row-major fp32
__global__ __launch_bounds__(256) void transpose_to_bf16(
        const float* __restrict__ src, unsigned short* __restrict__ dst,
        int K, int N) {
    __shared__ float tile[64][65];
    int k0 = blockIdx.x * 64, n0 = blockIdx.y * 64;
    int t = threadIdx.x;
    for (int i = 0; i < 16; ++i) {
        int idx = t + i * 256;
        int kk = idx >> 6, nn = idx & 63;
        tile[kk][nn] = src[(size_t)(k0 + kk) * N + (n0 + nn)];
    }
    __syncthreads();
    for (int i = 0; i < 16; ++i) {
        int idx = t + i * 256;
        int nn = idx >> 6, kk = idx & 63;
        dst[(size_t)(n0 + nn) * K + (k0 + kk)] = f2b(tile[kk][nn]);
    }
}

__device__ __forceinline__ int row_tag(const float* obs, int row) {
    float c2 = obs[(size_t)row * DIN + 2];
    float c3 = obs[(size_t)row * DIN + 3];
    return (c2 == 1.0f && c3 == 0.0f) ? 1 : 0;
}

__global__ __launch_bounds__(256) void tag_count(const float* __restrict__ obs,
                                                 int* __restrict__ cnt) {
    int t = threadIdx.x;
    int tag = row_tag(obs, blockIdx.x * 256 + t);
    unsigned long long m = __ballot(tag);
    __shared__ int wc[4];
    if ((t & 63) == 0) wc[t >> 6] = __popcll(m);
    __syncthreads();
    if (t == 0) cnt[blockIdx.x] = wc[0] + wc[1] + wc[2] + wc[3];
}

__global__ __launch_bounds__(256) void scan256(const int* __restrict__ cnt,
                                               int* __restrict__ offs) {
    __shared__ int s[256];
    int t = threadIdx.x;
    s[t] = cnt[t];
    __syncthreads();
    for (int d = 1; d < 256; d <<= 1) {
        int v = (t >= d) ? s[t - d] : 0;
        __syncthreads();
        s[t] += v;
        __syncthreads();
    }
    offs[t] = s[t] - cnt[t];
    if (t == 255) offs[256] = s[255];
}

// unified perm: U = [tag==1 rows (branch b)] ++ [tag==0 rows (branch c)]
__global__ __launch_bounds__(256) void fill_permU(const float* __restrict__ obs,
                                                  const int* __restrict__ offs,
                                                  int* __restrict__ U) {
    int t = threadIdx.x, bid = blockIdx.x;
    int row = bid * 256 + t;
    int tag = row_tag(obs, row);
    unsigned long long m = __ballot(tag);
    __shared__ int wc[4];
    int lane = t & 63, wv = t >> 6;
    if (lane == 0) wc[wv] = __popcll(m);
    __syncthreads();
    int woff = 0;
    for (int i = 0; i < 4; ++i) if (i < wv) woff += wc[i];
    int lb = woff + __popcll(m & ((1ull << lane) - 1ull));
    int base_b = offs[bid];
    int nb = offs[256];
    if (tag) U[base_b + lb] = row;
    else     U[nb + bid * 256 - base_b + (t - lb)] = row;
}

// LDS map (dynamic, 154112 B, 1 block/CU). R15 delta vs R14 (341.8 us):
// EXACT-1024 grid. Unified perm U gives exactly 512 expert tiles; the single
// b/c straddle tile is a 2-pass "mixed" block mapped to blockIdx 0 (dispatched
// first -> its 2x weight hides in rounds 1-2; makespan drops 5T -> 4T).
// Hot-loop schedule is byte-identical to R14's proven counted-vmcnt engine:
//   B1 vmcnt(2) | B2 vmcnt(0) | B3 vmcnt(0) | B4 vmcnt(4) | B5 vmcnt(2)
//   ldsX   @ 0      [128][256] bf16 = 64K  persistent, swz (r&7)<<4
//   ldsW1  @ 65536  [64][256]  bf16 = 32K  single-buffered W1 chunk
//   ldsQA  @ 98304  [128][64]  bf16 = 16K  W2 quarter ping
//   ldsQB  @ 114688 [128][64]  bf16 = 16K  W2 quarter pong
//   ldsH   @ 131072 [128][64]  bf16 = 16K
//   ldsB1  @ 147456 float[1024]
//   ldsB2  @ 151552 float[512]
//   ldsPr  @ 153600 int[128]
__global__ __launch_bounds__(512, 2) void fused_mlp(
    const float* __restrict__ obs,
    const unsigned short* __restrict__ wts,
    const int* __restrict__ U, const int* __restrict__ offs,
    const float* __restrict__ b1_0, const float* __restrict__ b2_0,
    const float* __restrict__ b1_1, const float* __restrict__ b2_1,
    const float* __restrict__ b1_2, const float* __restrict__ b2_2,
    float* __restrict__ out)
{
    extern __shared__ char lds[];
    char* ldsX  = lds;
    char* ldsW1 = lds + 65536;
    char* ldsQA = lds + 98304;
    char* ldsQB = lds + 114688;
    char* ldsH  = lds + 131072;
    float* ldsB1 = (float*)(lds + 147456);
    float* ldsB2 = (float*)(lds + 151552);
    int*  ldsPr  = (int*)(lds + 153600);

    // bijective swizzle over 1024 = 8*128: XCD (ob&7) gets contiguous wids;
    // ob=0 -> wid=0 = the double-weight mixed block (dispatched first).
    const int ob = blockIdx.x;
    const int wid = (ob & 7) * 128 + (ob >> 3);

    const int nb = offs[256];
    int e_mix = nb >> 7; if (e_mix > 511) e_mix = 511;
    const int rb = nb - e_mix * 128;   // 0..128

    int base, npass, brA, loA, hiA;
    int brB = 1, loB = 0, hiB = 0;
    bool usePerm;
    if (wid == 0) {                        // mixed straddle expert tile
        base = e_mix * 128; usePerm = true;
        if (rb > 0 && rb < 128) { npass = 2; brA = 0; loA = 0; hiA = rb;
                                  brB = 1; loB = rb; hiB = 128; }
        else if (rb == 0)       { npass = 1; brA = 1; loA = 0; hiA = 128; }
        else                    { npass = 1; brA = 0; loA = 0; hiA = 128; }
    } else if (wid <= 512) {               // streaming p tile
        base = (wid - 1) * 128; usePerm = false;
        npass = 1; brA = 2; loA = 0; hiA = 128;
    } else {                               // pure expert tile (skip e_mix)
        int j = wid - 513;
        int e = (j < e_mix) ? j : j + 1;
        base = e * 128; usePerm = true;
        npass = 1; brA = (e < e_mix) ? 0 : 1; loA = 0; hiA = 128;
    }

    const int t = threadIdx.x;
    const int lane = t & 63;
    const int w = t >> 6;
    const int l15 = lane & 15;
    const int g = lane >> 4;

    // ---- block prologue (shared by both passes): Pr table + X staging
    if (t < 128) ldsPr[t] = usePerm ? U[base + t] : (base + t);
    #pragma unroll
    for (int i = 0; i < 16; ++i) {
        int idx = t + i * 512;
        int r = idx >> 6, c4 = idx & 63;
        int grow = usePerm ? U[base + r] : (base + r);
        f32x4 v = *(const f32x4*)(obs + (size_t)grow * DIN + c4 * 4);
        ushort4 p4;
        p4.x = f2b(v.x); p4.y = f2b(v.y); p4.z = f2b(v.z); p4.w = f2b(v.w);
        *(ushort4*)(ldsX + r * 512 + ((c4 * 8) ^ ((r & 7) << 4))) = p4;
    }

    // wave roles
    const int rg = w & 3, cg = w >> 2;   // GEMM1: rows rg*32, hcols cg*32
    const int wr = w >> 2, wc = w & 3;   // GEMM2: rows wr*64, fcols wc*32/quarter

    const int ar0 = rg * 32 + l15, ar1 = ar0 + 16;
    const int asw0 = (ar0 & 7) << 4, asw1 = (ar1 & 7) << 4;
    const int bn0 = cg * 32 + l15, bn1 = bn0 + 16;
    const int bsw0 = (bn0 & 7) << 4, bsw1 = (bn1 & 7) << 4;

    #define STAGE_Q(buf, q, hc_)                                               \
        {                                                                      \
            _Pragma("unroll")                                                  \
            for (int i = 0; i < 2; ++i) {                                      \
                int slot = t + i * 512;                                        \
                int nl = slot >> 3, boff = (slot & 7) << 4;                    \
                gll16(w2t + (size_t)((q) * 128 + nl) * 2048 + (hc_) * 128      \
                          + (boff ^ ((nl & 7) << 4)),                          \
                      (buf) + slot * 16);                                      \
            }                                                                  \
        }

    #define STAGE_W1(hc_)                                                      \
        {                                                                      \
            _Pragma("unroll")                                                  \
            for (int i = 0; i < 4; ++i) {                                      \
                int slot = t + i * 512;                                        \
                int nl = slot >> 5, boff = (slot & 31) << 4;                   \
                gll16(w1t + (size_t)((hc_) * 64 + nl) * 512 + (boff ^ ((nl & 7) << 4)), \
                      ldsW1 + slot * 16);                                      \
            }                                                                  \
        }

    #define QUARTER_MFMA(buf, c0)                                              \
        {                                                                      \
            _Pragma("unroll")                                                  \
            for (int k2 = 0; k2 < 2; ++k2)                                     \
                _Pragma("unroll")                                              \
                for (int ct = 0; ct < 2; ++ct) {                               \
                    int fr = wc * 32 + ct * 16 + l15;                          \
                    bf16x8 bb = *(const bf16x8*)((buf) + fr * 128 +            \
                                 ((k2 * 64 + g * 16) ^ ((fr & 7) << 4)));      \
                    _Pragma("unroll")                                          \
                    for (int rt = 0; rt < 4; ++rt)                             \
                        acc[rt][(c0) + ct] = __builtin_amdgcn_mfma_f32_16x16x32_bf16( \
                            hA[rt][k2], bb, acc[rt][(c0) + ct], 0, 0, 0);      \
                }                                                              \
        }

    for (int pass = 0; pass < npass; ++pass) {
        const int branch = (pass == 0) ? brA : brB;
        const int rlo = (pass == 0) ? loA : loB;
        const int rhi = (pass == 0) ? hiA : hiB;
        const float* b1 = branch == 0 ? b1_0 : (branch == 1 ? b1_1 : b1_2);
        const float* b2 = branch == 0 ? b2_0 : (branch == 1 ? b2_1 : b2_2);
        const char* w1t = (const char*)(wts + (size_t)branch * (DH * DIN));
        const char* w2t = (const char*)(wts + (size_t)3 * DH * DIN + (size_t)branch * (DF * DH));

        // per-pass tables (vector loads; force-drained before counted stages)
        ldsB1[t] = b1[t];
        ldsB1[t + 512] = b1[t + 512];
        ldsB2[t] = b2[t];
        DRAIN_VM();

        // pass prologue prefetch: W1[0] (4 loads), then q0 of chunk 0 (2)
        STAGE_W1(0);
        STAGE_Q(ldsQA, 0, 0);
        BAR_V(2);   // retire W1[0]; q0 stays in flight

        f32x4 acc[4][8];
        #pragma unroll
        for (int a = 0; a < 4; ++a)
            #pragma unroll
            for (int b = 0; b < 8; ++b)
                #pragma unroll
                for (int e = 0; e < 4; ++e) acc[a][b][e] = 0.0f;

        for (int hc = 0; hc < 16; ++hc) {
            // ---- I1: stage q1->QB ; GEMM1 + bias/relu -> H
            STAGE_Q(ldsQB, 1, hc);
            f32x4 aH[2][2];
            #pragma unroll
            for (int a = 0; a < 2; ++a)
                #pragma unroll
                for (int b = 0; b < 2; ++b)
                    #pragma unroll
                    for (int e = 0; e < 4; ++e) aH[a][b][e] = 0.0f;
            __builtin_amdgcn_s_setprio(1);
            #pragma unroll
            for (int kk = 0; kk < 8; ++kk) {
                int kb = kk * 64 + g * 16;
                bf16x8 a0 = *(const bf16x8*)(ldsX  + ar0 * 512 + (kb ^ asw0));
                bf16x8 a1 = *(const bf16x8*)(ldsX  + ar1 * 512 + (kb ^ asw1));
                bf16x8 b0 = *(const bf16x8*)(ldsW1 + bn0 * 512 + (kb ^ bsw0));
                bf16x8 b1f = *(const bf16x8*)(ldsW1 + bn1 * 512 + (kb ^ bsw1));
                aH[0][0] = __builtin_amdgcn_mfma_f32_16x16x32_bf16(a0, b0,  aH[0][0], 0, 0, 0);
                aH[0][1] = __builtin_amdgcn_mfma_f32_16x16x32_bf16(a0, b1f, aH[0][1], 0, 0, 0);
                aH[1][0] = __builtin_amdgcn_mfma_f32_16x16x32_bf16(a1, b0,  aH[1][0], 0, 0, 0);
                aH[1][1] = __builtin_amdgcn_mfma_f32_16x16x32_bf16(a1, b1f, aH[1][1], 0, 0, 0);
            }
            __builtin_amdgcn_s_setprio(0);
            {
                float b1v0 = ldsB1[hc * 64 + cg * 32 + l15];
                float b1v1 = ldsB1[hc * 64 + cg * 32 + 16 + l15];
                #pragma unroll
                for (int art = 0; art < 2; ++art)
                    #pragma unroll
                    for (int bct = 0; bct < 2; ++bct) {
                        int col2 = (cg * 32 + bct * 16 + l15) * 2;
                        float bv = bct ? b1v1 : b1v0;
                        #pragma unroll
                        for (int r = 0; r < 4; ++r) {
                            int hrow = rg * 32 + art * 16 + g * 4 + r;
                            float vv = fmaxf(aH[art][bct][r] + bv, 0.0f);
                            *(unsigned short*)(ldsH + hrow * 128 + (col2 ^ ((hrow & 7) << 4))) = f2b(vv);
                        }
                    }
            }
            BAR_V(2);   // B1: retire q0 (keep q1); H visible

            // ---- I2: hA loads ; GEMM2 q0 (QA)
            bf16x8 hA[4][2];
            #pragma unroll
            for (int rt = 0; rt < 4; ++rt)
                #pragma unroll
                for (int k2 = 0; k2 < 2; ++k2) {
                    int hr = wr * 64 + rt * 16 + l15;
                    hA[rt][k2] = *(const bf16x8*)(ldsH + hr * 128 + ((k2 * 64 + g * 16) ^ ((hr & 7) << 4)));
                }
            __builtin_amdgcn_s_setprio(1);
            QUARTER_MFMA(ldsQA, 0);
            __builtin_amdgcn_s_setprio(0);
            BAR_V(0);   // B2: retire q1 (2-interval lead)

            // ---- I3: stage q2->QA ; GEMM2 q1 (QB)
            STAGE_Q(ldsQA, 2, hc);
            __builtin_amdgcn_s_setprio(1);
            QUARTER_MFMA(ldsQB, 2);
            __builtin_amdgcn_s_setprio(0);
            BAR_V(0);   // B3: retire q2

            // ---- I4: stage q3->QB ; stage W1[hc+1] ; GEMM2 q2 (QA)
            STAGE_Q(ldsQB, 3, hc);
            STAGE_W1((hc + 1) & 15);   // uniform count (wasted refetch hc=15)
            __builtin_amdgcn_s_setprio(1);
            QUARTER_MFMA(ldsQA, 4);
            __builtin_amdgcn_s_setprio(0);
            BAR_V(4);   // B4: retire q3 (keep W1')

            // ---- I5: stage next q0->QA ; GEMM2 q3 (QB)
            STAGE_Q(ldsQA, 0, (hc + 1) & 15);   // uniform count
            __builtin_amdgcn_s_setprio(1);
            QUARTER_MFMA(ldsQB, 6);
            __builtin_amdgcn_s_setprio(0);
            BAR_V(2);   // B5: retire W1' (keep next q0)
        }
        DRAIN_VM();   // retire dangling hc=15 prefetches

        // ---- epilogue: bias2 + masked permuted scatter store
        const int colbase = (branch == 2) ? DF : 0;
        int colq[8]; float b2v[8];
        #pragma unroll
        for (int q = 0; q < 8; ++q) {
            colq[q] = (q >> 1) * 128 + wc * 32 + (q & 1) * 16 + l15;
            b2v[q] = ldsB2[colq[q]];
        }
        #pragma unroll
        for (int rt = 0; rt < 4; ++rt)
            #pragma unroll
            for (int r = 0; r < 4; ++r) {
                int row = wr * 64 + rt * 16 + g * 4 + r;
                if (row >= rlo && row < rhi) {
                    int prow = ldsPr[row];
                    float* op = out + (size_t)prow * (2 * DF) + colbase;
                    #pragma unroll
                    for (int q = 0; q < 8; ++q)
                        op[colq[q]] = acc[rt][q][r] + b2v[q];
                }
            }
        __syncthreads();   // protect tables before a possible second pass
    }
}

extern "C" void kernel_launch(void* const* d_in, const int* in_sizes, int n_in,
                              void* d_out, int out_size, void* d_ws, size_t ws_size,
                              hipStream_t stream) {
    const float* obs = (const float*)d_in[0];
    const float* W1[3] = {(const float*)d_in[1], (const float*)d_in[5], (const float*)d_in[9]};
    const float* b1[3] = {(const float*)d_in[2], (const float*)d_in[6], (const float*)d_in[10]};
    const float* W2[3] = {(const float*)d_in[3], (const float*)d_in[7], (const float*)d_in[11]};
    const float* b2[3] = {(const float*)d_in[4], (const float*)d_in[8], (const float*)d_in[12]};

    char* ws = (char*)d_ws;
    unsigned short* wts = (unsigned short*)(ws + WS_WTS);
    int* U    = (int*)(ws + WS_U);
    int* cnt  = (int*)(ws + WS_CNT);
    int* offs = (int*)(ws + WS_OFFS);

    for (int br = 0; br < 3; ++br) {
        transpose_to_bf16<<<dim3(DIN / 64, DH / 64), 256, 0, stream>>>(
            W1[br], wts + (size_t)br * DH * DIN, DIN, DH);
        transpose_to_bf16<<<dim3(DH / 64, DF / 64), 256, 0, stream>>>(
            W2[br], wts + (size_t)3 * DH * DIN + (size_t)br * DF * DH, DH, DF);
    }
    tag_count<<<256, 256, 0, stream>>>(obs, cnt);
    scan256<<<1, 256, 0, stream>>>(cnt, offs);
    fill_permU<<<256, 256, 0, stream>>>(obs, offs, U);

    hipFuncSetAttribute((const void*)fused_mlp,
                        hipFuncAttributeMaxDynamicSharedMemorySize, 154112);
    fused_mlp<<<1024, 512, 154112, stream>>>(obs, wts, U, offs,
        b1[0], b2[0], b1[1], b2[1], b1[2], b2[2], (float*)d_out);
}

// Round 16
// 335.334 us; speedup vs baseline: 1.0531x; 1.0531x over previous
//
#include <hip/hip_runtime.h>
#include <hip/hip_bf16.h>

#define DIN 256
#define DH  1024
#define DF  512
#define NROWS 65536

// workspace layout (bytes)
#define WS_WTS   0
#define WS_PB    4718592
#define WS_PC    4980736
#define WS_CNT   5242880
#define WS_OFFS  5243904

typedef __attribute__((ext_vector_type(8))) short bf16x8;
typedef __attribute__((ext_vector_type(4))) float f32x4;

__device__ __forceinline__ unsigned short f2b(float f) {
    union { float f; unsigned u; } v; v.f = f;
    unsigned r = v.u + 0x7FFFu + ((v.u >> 16) & 1u);
    return (unsigned short)(r >> 16);
}

__device__ __forceinline__ void gll16(const void* g, void* l) {
    __builtin_amdgcn_global_load_lds(
        (const __attribute__((address_space(1))) void*)g,
        (__attribute__((address_space(3))) void*)l, 16, 0, 0);
}

// counted waits: loop VMEM stream is EXACTLY the gll16s, so vmcnt counts are
// provable (tables/prologue loads force-drained first).
#define BAR_V(N) asm volatile("s_waitcnt vmcnt(" #N ") lgkmcnt(0)\ns_barrier" ::: "memory")
#define DRAIN_VM() asm volatile("s_waitcnt vmcnt(0)" ::: "memory")

// dst[n][k] = (bf16) src[k][n] ; src is K x N row-major fp32
__global__ __launch_bounds__(256) void transpose_to_bf16(
        const float* __restrict__ src, unsigned short* __restrict__ dst,
        int K, int N) {
    __shared__ float tile[64][65];
    int k0 = blockIdx.x * 64, n0 = blockIdx.y * 64;
    int t = threadIdx.x;
    for (int i = 0; i < 16; ++i) {
        int idx = t + i * 256;
        int kk = idx >> 6, nn = idx & 63;
        tile[kk][nn] = src[(size_t)(k0 + kk) * N + (n0 + nn)];
    }
    __syncthreads();
    for (int i = 0; i < 16; ++i) {
        int idx = t + i * 256;
        int nn = idx >> 6, kk = idx & 63;
        dst[(size_t)(n0 + nn) * K + (k0 + kk)] = f2b(tile[kk][nn]);
    }
}

__device__ __forceinline__ int row_tag(const float* obs, int row) {
    float c2 = obs[(size_t)row * DIN + 2];
    float c3 = obs[(size_t)row * DIN + 3];
    return (c2 == 1.0f && c3 == 0.0f) ? 1 : 0;
}

__global__ __launch_bounds__(256) void tag_count(const float* __restrict__ obs,
                                                 int* __restrict__ cnt) {
    int t = threadIdx.x;
    int tag = row_tag(obs, blockIdx.x * 256 + t);
    unsigned long long m = __ballot(tag);
    __shared__ int wc[4];
    if ((t & 63) == 0) wc[t >> 6] = __popcll(m);
    __syncthreads();
    if (t == 0) cnt[blockIdx.x] = wc[0] + wc[1] + wc[2] + wc[3];
}

__global__ __launch_bounds__(256) void scan256(const int* __restrict__ cnt,
                                               int* __restrict__ offs) {
    __shared__ int s[256];
    int t = threadIdx.x;
    s[t] = cnt[t];
    __syncthreads();
    for (int d = 1; d < 256; d <<= 1) {
        int v = (t >= d) ? s[t - d] : 0;
        __syncthreads();
        s[t] += v;
        __syncthreads();
    }
    offs[t] = s[t] - cnt[t];
    if (t == 255) offs[256] = s[255];
}

__global__ __launch_bounds__(256) void fill_perm(const float* __restrict__ obs,
                                                 const int* __restrict__ offs,
                                                 int* __restrict__ pb,
                                                 int* __restrict__ pc) {
    int t = threadIdx.x, bid = blockIdx.x;
    int row = bid * 256 + t;
    int tag = row_tag(obs, row);
    unsigned long long m = __ballot(tag);
    __shared__ int wc[4];
    int lane = t & 63, wv = t >> 6;
    if (lane == 0) wc[wv] = __popcll(m);
    __syncthreads();
    int woff = 0;
    for (int i = 0; i < 4; ++i) if (i < wv) woff += wc[i];
    int lb = woff + __popcll(m & ((1ull << lane) - 1ull));
    int base_b = offs[bid];
    if (tag) pb[base_b + lb] = row;
    else     pc[bid * 256 - base_b + (t - lb)] = row;
}

// LDS map (dynamic, 154112 B, 1 block/CU). R16 = R14's proven counted-vmcnt
// engine (342 us) + cheap-tail: grid 1026; obs 1024/1025 (dispatched LAST =
// the round-5 pair) are column-half blocks of p-tile 511 on a 3-interval
// counted loop. Total units 1025 can't pack into 4 rounds (5T floor with
// atomic T-blocks); splitting the overflow unit gives 4T + ~0.7T.
// Full-path barriers (R14): B1 v(2) | B2 v(0) | B3 v(0) | B4 v(4) | B5 v(2)
// Half-path barriers:       B1 v(2) | B2 v(4) | B3 v(2)
//   (per chunk: I1 stage qhi(2), GEMM1, H | I2 hA, MFMA qlo, stage W1'(4) |
//    I3 stage next qlo(2), MFMA qhi.  WAR: QA r(I2) w(I3) sep B2; QB w(I1)
//    r(I3), prev r(I3) vs w(I1) sep B3; W1 r(I1) w(I2) sep B1; H w(I1) r(I2)
//    sep B1 lgkm. Counts: B1 out={qlo2,qhi2}->v2 retires qlo; B2
//    out={qhi2,W1'4}->v4 retires qhi; B3 out={W1'4,qlo2}->v2 retires W1'.)
//   ldsX   @ 0      [128][256] bf16 = 64K  persistent, swz (r&7)<<4
//   ldsW1  @ 65536  [64][256]  bf16 = 32K  single-buffered W1 chunk
//   ldsQA  @ 98304  [128][64]  bf16 = 16K  W2 quarter ping
//   ldsQB  @ 114688 [128][64]  bf16 = 16K  W2 quarter pong
//   ldsH   @ 131072 [128][64]  bf16 = 16K
//   ldsB1  @ 147456 float[1024]
//   ldsB2  @ 151552 float[512]
//   ldsPr  @ 153600 int[128]
__global__ __launch_bounds__(512, 2) void fused_mlp(
    const float* __restrict__ obs,
    const unsigned short* __restrict__ wts,
    const int* __restrict__ perm_b, const int* __restrict__ perm_c,
    const int* __restrict__ offs,
    const float* __restrict__ b1_0, const float* __restrict__ b2_0,
    const float* __restrict__ b1_1, const float* __restrict__ b2_1,
    const float* __restrict__ b1_2, const float* __restrict__ b2_2,
    float* __restrict__ out)
{
    extern __shared__ char lds[];
    char* ldsX  = lds;
    char* ldsW1 = lds + 65536;
    char* ldsQA = lds + 98304;
    char* ldsQB = lds + 114688;
    char* ldsH  = lds + 131072;
    float* ldsB1 = (float*)(lds + 147456);
    float* ldsB2 = (float*)(lds + 151552);
    int*  ldsPr  = (int*)(lds + 153600);

    const int ob = blockIdx.x;
    int branch, base, cnt, half = -1;
    const int* perm;
    if (ob >= 1024) {
        // tail pair: column-halves of p-tile 511 (runs in round 5)
        half = ob - 1024;             // 0: cols 0..255, 1: cols 256..511
        branch = 2; base = 511 * 128; cnt = NROWS; perm = nullptr;
    } else {
        // bijective XCD swizzle over 1024 = 8*128: XCD gets contiguous wids
        const int wid = (ob & 7) * 128 + (ob >> 3);
        if (wid < 511) {
            branch = 2; base = wid * 128; cnt = NROWS; perm = nullptr;
        } else {
            int eb = wid - 511;       // 0..512 -> 513 expert slots
            int nb = offs[256];
            int nbb = (nb + 127) >> 7;
            int nc = NROWS - nb;
            int ncb = (nc + 127) >> 7;
            if (eb < nbb)            { branch = 0; base = eb * 128;         cnt = nb; perm = perm_b; }
            else if (eb < nbb + ncb) { branch = 1; base = (eb - nbb) * 128; cnt = nc; perm = perm_c; }
            else return;
        }
    }

    const float* b1 = branch == 0 ? b1_0 : (branch == 1 ? b1_1 : b1_2);
    const float* b2 = branch == 0 ? b2_0 : (branch == 1 ? b2_1 : b2_2);
    const char* w1t = (const char*)(wts + (size_t)branch * (DH * DIN));
    const char* w2t = (const char*)(wts + (size_t)3 * DH * DIN + (size_t)branch * (DF * DH));

    const int t = threadIdx.x;
    const int lane = t & 63;
    const int w = t >> 6;
    const int l15 = lane & 15;
    const int g = lane >> 4;

    // ---- prologue: tables + X staging (all non-gll16 VMEM lives here)
    ldsB1[t] = b1[t];
    ldsB1[t + 512] = b1[t + 512];
    ldsB2[t] = b2[t];
    if (t < 128) {
        int gr = base + t;
        ldsPr[t] = (gr < cnt) ? (perm ? perm[gr] : gr) : -1;
    }
    #pragma unroll
    for (int i = 0; i < 16; ++i) {
        int idx = t + i * 512;
        int r = idx >> 6, c4 = idx & 63;
        int gr = base + r;
        int grow = gr < cnt ? gr : cnt - 1;
        if (perm) grow = perm[grow];
        f32x4 v = *(const f32x4*)(obs + (size_t)grow * DIN + c4 * 4);
        ushort4 p4;
        p4.x = f2b(v.x); p4.y = f2b(v.y); p4.z = f2b(v.z); p4.w = f2b(v.w);
        *(ushort4*)(ldsX + r * 512 + ((c4 * 8) ^ ((r & 7) << 4))) = p4;
    }
    DRAIN_VM();   // force-drain obs/table loads so loop vmcnt counts are exact

    #define STAGE_Q(buf, q, hc_)                                               \
        {                                                                      \
            _Pragma("unroll")                                                  \
            for (int i = 0; i < 2; ++i) {                                      \
                int slot = t + i * 512;                                        \
                int nl = slot >> 3, boff = (slot & 7) << 4;                    \
                gll16(w2t + (size_t)((q) * 128 + nl) * 2048 + (hc_) * 128      \
                          + (boff ^ ((nl & 7) << 4)),                          \
                      (buf) + slot * 16);                                      \
            }                                                                  \
        }

    #define STAGE_W1(hc_)                                                      \
        {                                                                      \
            _Pragma("unroll")                                                  \
            for (int i = 0; i < 4; ++i) {                                      \
                int slot = t + i * 512;                                        \
                int nl = slot >> 5, boff = (slot & 31) << 4;                   \
                gll16(w1t + (size_t)((hc_) * 64 + nl) * 512 + (boff ^ ((nl & 7) << 4)), \
                      ldsW1 + slot * 16);                                      \
            }                                                                  \
        }

    // wave roles
    const int rg = w & 3, cg = w >> 2;   // GEMM1: rows rg*32, hcols cg*32
    const int wr = w >> 2, wc = w & 3;   // GEMM2: rows wr*64, fcols wc*32/quarter

    const int ar0 = rg * 32 + l15, ar1 = ar0 + 16;
    const int asw0 = (ar0 & 7) << 4, asw1 = (ar1 & 7) << 4;
    const int bn0 = cg * 32 + l15, bn1 = bn0 + 16;
    const int bsw0 = (bn0 & 7) << 4, bsw1 = (bn1 & 7) << 4;

    f32x4 acc[4][8];
    #pragma unroll
    for (int a = 0; a < 4; ++a)
        #pragma unroll
        for (int b = 0; b < 8; ++b)
            #pragma unroll
            for (int e = 0; e < 4; ++e) acc[a][b][e] = 0.0f;

    #define GEMM1_BODY(hc_)                                                    \
        f32x4 aH[2][2];                                                        \
        _Pragma("unroll")                                                      \
        for (int a = 0; a < 2; ++a)                                            \
            _Pragma("unroll")                                                  \
            for (int b = 0; b < 2; ++b)                                        \
                _Pragma("unroll")                                              \
                for (int e = 0; e < 4; ++e) aH[a][b][e] = 0.0f;                \
        __builtin_amdgcn_s_setprio(1);                                         \
        _Pragma("unroll")                                                      \
        for (int kk = 0; kk < 8; ++kk) {                                       \
            int kb = kk * 64 + g * 16;                                         \
            bf16x8 a0 = *(const bf16x8*)(ldsX  + ar0 * 512 + (kb ^ asw0));     \
            bf16x8 a1 = *(const bf16x8*)(ldsX  + ar1 * 512 + (kb ^ asw1));     \
            bf16x8 b0 = *(const bf16x8*)(ldsW1 + bn0 * 512 + (kb ^ bsw0));     \
            bf16x8 b1f = *(const bf16x8*)(ldsW1 + bn1 * 512 + (kb ^ bsw1));    \
            aH[0][0] = __builtin_amdgcn_mfma_f32_16x16x32_bf16(a0, b0,  aH[0][0], 0, 0, 0); \
            aH[0][1] = __builtin_amdgcn_mfma_f32_16x16x32_bf16(a0, b1f, aH[0][1], 0, 0, 0); \
            aH[1][0] = __builtin_amdgcn_mfma_f32_16x16x32_bf16(a1, b0,  aH[1][0], 0, 0, 0); \
            aH[1][1] = __builtin_amdgcn_mfma_f32_16x16x32_bf16(a1, b1f, aH[1][1], 0, 0, 0); \
        }                                                                      \
        __builtin_amdgcn_s_setprio(0);                                         \
        {                                                                      \
            float b1v0 = ldsB1[(hc_) * 64 + cg * 32 + l15];                    \
            float b1v1 = ldsB1[(hc_) * 64 + cg * 32 + 16 + l15];               \
            _Pragma("unroll")                                                  \
            for (int art = 0; art < 2; ++art)                                  \
                _Pragma("unroll")                                              \
                for (int bct = 0; bct < 2; ++bct) {                            \
                    int col2 = (cg * 32 + bct * 16 + l15) * 2;                 \
                    float bv = bct ? b1v1 : b1v0;                              \
                    _Pragma("unroll")                                          \
                    for (int r = 0; r < 4; ++r) {                              \
                        int hrow = rg * 32 + art * 16 + g * 4 + r;             \
                        float vv = fmaxf(aH[art][bct][r] + bv, 0.0f);          \
                        *(unsigned short*)(ldsH + hrow * 128 + (col2 ^ ((hrow & 7) << 4))) = f2b(vv); \
                    }                                                          \
                }                                                              \
        }

    #define LOAD_HA()                                                          \
        bf16x8 hA[4][2];                                                       \
        _Pragma("unroll")                                                      \
        for (int rt = 0; rt < 4; ++rt)                                         \
            _Pragma("unroll")                                                  \
            for (int k2 = 0; k2 < 2; ++k2) {                                   \
                int hr = wr * 64 + rt * 16 + l15;                              \
                hA[rt][k2] = *(const bf16x8*)(ldsH + hr * 128 + ((k2 * 64 + g * 16) ^ ((hr & 7) << 4))); \
            }

    #define QUARTER_MFMA(buf, c0)                                              \
        {                                                                      \
            _Pragma("unroll")                                                  \
            for (int k2 = 0; k2 < 2; ++k2)                                     \
                _Pragma("unroll")                                              \
                for (int ct = 0; ct < 2; ++ct) {                               \
                    int fr = wc * 32 + ct * 16 + l15;                          \
                    bf16x8 bb = *(const bf16x8*)((buf) + fr * 128 +            \
                                 ((k2 * 64 + g * 16) ^ ((fr & 7) << 4)));      \
                    _Pragma("unroll")                                          \
                    for (int rt = 0; rt < 4; ++rt)                             \
                        acc[rt][(c0) + ct] = __builtin_amdgcn_mfma_f32_16x16x32_bf16( \
                            hA[rt][k2], bb, acc[rt][(c0) + ct], 0, 0, 0);      \
                }                                                              \
        }

    if (half < 0) {
        // =================== FULL path (R14 engine, unchanged) ===============
        STAGE_W1(0);
        STAGE_Q(ldsQA, 0, 0);
        BAR_V(2);   // retire W1[0]; q0 stays in flight

        for (int hc = 0; hc < 16; ++hc) {
            // I1: stage q1->QB ; GEMM1 + bias/relu -> H
            STAGE_Q(ldsQB, 1, hc);
            GEMM1_BODY(hc);
            BAR_V(2);   // B1: retire q0 (keep q1); H visible

            // I2: hA loads ; GEMM2 q0 (QA)
            LOAD_HA();
            __builtin_amdgcn_s_setprio(1);
            QUARTER_MFMA(ldsQA, 0);
            __builtin_amdgcn_s_setprio(0);
            BAR_V(0);   // B2: retire q1 (2-interval lead)

            // I3: stage q2->QA ; GEMM2 q1 (QB)
            STAGE_Q(ldsQA, 2, hc);
            __builtin_amdgcn_s_setprio(1);
            QUARTER_MFMA(ldsQB, 2);
            __builtin_amdgcn_s_setprio(0);
            BAR_V(0);   // B3: retire q2

            // I4: stage q3->QB ; stage W1[hc+1] ; GEMM2 q2 (QA)
            STAGE_Q(ldsQB, 3, hc);
            STAGE_W1((hc + 1) & 15);
            __builtin_amdgcn_s_setprio(1);
            QUARTER_MFMA(ldsQA, 4);
            __builtin_amdgcn_s_setprio(0);
            BAR_V(4);   // B4: retire q3 (keep W1')

            // I5: stage next q0->QA ; GEMM2 q3 (QB)
            STAGE_Q(ldsQA, 0, (hc + 1) & 15);
            __builtin_amdgcn_s_setprio(1);
            QUARTER_MFMA(ldsQB, 6);
            __builtin_amdgcn_s_setprio(0);
            BAR_V(2);   // B5: retire W1' (keep next q0)
        }
        DRAIN_VM();

        // epilogue: bias2 + permuted scatter store
        int colq[8]; float b2v[8];
        #pragma unroll
        for (int q = 0; q < 8; ++q) {
            colq[q] = (q >> 1) * 128 + wc * 32 + (q & 1) * 16 + l15;
            b2v[q] = ldsB2[colq[q]];
        }
        const int cb = (branch == 2) ? DF : 0;
        #pragma unroll
        for (int rt = 0; rt < 4; ++rt)
            #pragma unroll
            for (int r = 0; r < 4; ++r) {
                int row = wr * 64 + rt * 16 + g * 4 + r;
                int prow = ldsPr[row];
                if (prow >= 0) {
                    float* op = out + (size_t)prow * (2 * DF) + cb;
                    #pragma unroll
                    for (int q = 0; q < 8; ++q)
                        op[colq[q]] = acc[rt][q][r] + b2v[q];
                }
            }
    } else {
        // =================== HALF path (tail pair, 3 intervals) ==============
        const int qlo = half * 2, qhi = qlo + 1;
        STAGE_W1(0);
        if (half == 0) { STAGE_Q(ldsQA, 0, 0); } else { STAGE_Q(ldsQA, 2, 0); }
        BAR_V(2);   // retire W1[0]; qlo stays in flight

        for (int hc = 0; hc < 16; ++hc) {
            // I1: stage qhi->QB ; GEMM1 + bias/relu -> H
            if (half == 0) { STAGE_Q(ldsQB, 1, hc); } else { STAGE_Q(ldsQB, 3, hc); }
            GEMM1_BODY(hc);
            BAR_V(2);   // B1: retire qlo (keep qhi); H visible

            // I2: hA ; stage W1' ; GEMM2 qlo (QA)
            LOAD_HA();
            STAGE_W1((hc + 1) & 15);
            __builtin_amdgcn_s_setprio(1);
            QUARTER_MFMA(ldsQA, 0);
            __builtin_amdgcn_s_setprio(0);
            BAR_V(4);   // B2: retire qhi (keep W1')

            // I3: stage next qlo->QA ; GEMM2 qhi (QB)
            if (half == 0) { STAGE_Q(ldsQA, 0, (hc + 1) & 15); }
            else           { STAGE_Q(ldsQA, 2, (hc + 1) & 15); }
            __builtin_amdgcn_s_setprio(1);
            QUARTER_MFMA(ldsQB, 2);
            __builtin_amdgcn_s_setprio(0);
            BAR_V(2);   // B3: retire W1' (keep next qlo)
        }
        DRAIN_VM();

        // epilogue: 4 col-groups of this half (global col = half*256 + colq)
        int colq[4]; float b2v[4];
        #pragma unroll
        for (int q = 0; q < 4; ++q) {
            colq[q] = (q >> 1) * 128 + wc * 32 + (q & 1) * 16 + l15;
            b2v[q] = ldsB2[half * 256 + colq[q]];
        }
        const int cb = DF + half * 256;   // tail blocks are branch p
        #pragma unroll
        for (int rt = 0; rt < 4; ++rt)
            #pragma unroll
            for (int r = 0; r < 4; ++r) {
                int row = wr * 64 + rt * 16 + g * 4 + r;
                int prow = ldsPr[row];
                if (prow >= 0) {
                    float* op = out + (size_t)prow * (2 * DF) + cb;
                    #pragma unroll
                    for (int q = 0; q < 4; ++q)
                        op[colq[q]] = acc[rt][q][r] + b2v[q];
                }
            }
    }
}

extern "C" void kernel_launch(void* const* d_in, const int* in_sizes, int n_in,
                              void* d_out, int out_size, void* d_ws, size_t ws_size,
                              hipStream_t stream) {
    const float* obs = (const float*)d_in[0];
    const float* W1[3] = {(const float*)d_in[1], (const float*)d_in[5], (const float*)d_in[9]};
    const float* b1[3] = {(const float*)d_in[2], (const float*)d_in[6], (const float*)d_in[10]};
    const float* W2[3] = {(const float*)d_in[3], (const float*)d_in[7], (const float*)d_in[11]};
    const float* b2[3] = {(const float*)d_in[4], (const float*)d_in[8], (const float*)d_in[12]};

    char* ws = (char*)d_ws;
    unsigned short* wts = (unsigned short*)(ws + WS_WTS);
    int* pb   = (int*)(ws + WS_PB);
    int* pc   = (int*)(ws + WS_PC);
    int* cnt  = (int*)(ws + WS_CNT);
    int* offs = (int*)(ws + WS_OFFS);

    for (int br = 0; br < 3; ++br) {
        transpose_to_bf16<<<dim3(DIN / 64, DH / 64), 256, 0, stream>>>(
            W1[br], wts + (size_t)br * DH * DIN, DIN, DH);
        transpose_to_bf16<<<dim3(DH / 64, DF / 64), 256, 0, stream>>>(
            W2[br], wts + (size_t)3 * DH * DIN + (size_t)br * DF * DH, DH, DF);
    }
    tag_count<<<256, 256, 0, stream>>>(obs, cnt);
    scan256<<<1, 256, 0, stream>>>(cnt, offs);
    fill_perm<<<256, 256, 0, stream>>>(obs, offs, pb, pc);

    hipFuncSetAttribute((const void*)fused_mlp,
                        hipFuncAttributeMaxDynamicSharedMemorySize, 154112);
    fused_mlp<<<1026, 512, 154112, stream>>>(obs, wts, pb, pc, offs,
        b1[0], b2[0], b1[1], b2[1], b1[2], b2[2], (float*)d_out);
}

// Round 17
// 327.459 us; speedup vs baseline: 1.0784x; 1.0241x over previous
//
#include <hip/hip_runtime.h>
#include <hip/hip_bf16.h>

#define DIN 256
#define DH  1024
#define DF  512
#define NROWS 65536

// workspace layout (bytes)
#define WS_WTS   0
#define WS_PB    4718592
#define WS_PC    4980736
#define WS_CNT   5242880
#define WS_OFFS  5243904

typedef __attribute__((ext_vector_type(8))) short bf16x8;
typedef __attribute__((ext_vector_type(4))) float f32x4;

__device__ __forceinline__ unsigned short f2b(float f) {
    union { float f; unsigned u; } v; v.f = f;
    unsigned r = v.u + 0x7FFFu + ((v.u >> 16) & 1u);
    return (unsigned short)(r >> 16);
}

__device__ __forceinline__ void gll16(const void* g, void* l) {
    __builtin_amdgcn_global_load_lds(
        (const __attribute__((address_space(1))) void*)g,
        (__attribute__((address_space(3))) void*)l, 16, 0, 0);
}

// counted waits: loop VMEM stream is EXACTLY the gll16s, so vmcnt counts are
// provable (tables/prologue loads force-drained first).
#define BAR_V(N) asm volatile("s_waitcnt vmcnt(" #N ") lgkmcnt(0)\ns_barrier" ::: "memory")
#define DRAIN_VM() asm volatile("s_waitcnt vmcnt(0)" ::: "memory")

// dst[n][k] = (bf16) src[k][n] ; src is K x N row-major fp32
__global__ __launch_bounds__(256) void transpose_to_bf16(
        const float* __restrict__ src, unsigned short* __restrict__ dst,
        int K, int N) {
    __shared__ float tile[64][65];
    int k0 = blockIdx.x * 64, n0 = blockIdx.y * 64;
    int t = threadIdx.x;
    for (int i = 0; i < 16; ++i) {
        int idx = t + i * 256;
        int kk = idx >> 6, nn = idx & 63;
        tile[kk][nn] = src[(size_t)(k0 + kk) * N + (n0 + nn)];
    }
    __syncthreads();
    for (int i = 0; i < 16; ++i) {
        int idx = t + i * 256;
        int nn = idx >> 6, kk = idx & 63;
        dst[(size_t)(n0 + nn) * K + (k0 + kk)] = f2b(tile[kk][nn]);
    }
}

__device__ __forceinline__ int row_tag(const float* obs, int row) {
    float c2 = obs[(size_t)row * DIN + 2];
    float c3 = obs[(size_t)row * DIN + 3];
    return (c2 == 1.0f && c3 == 0.0f) ? 1 : 0;
}

__global__ __launch_bounds__(256) void tag_count(const float* __restrict__ obs,
                                                 int* __restrict__ cnt) {
    int t = threadIdx.x;
    int tag = row_tag(obs, blockIdx.x * 256 + t);
    unsigned long long m = __ballot(tag);
    __shared__ int wc[4];
    if ((t & 63) == 0) wc[t >> 6] = __popcll(m);
    __syncthreads();
    if (t == 0) cnt[blockIdx.x] = wc[0] + wc[1] + wc[2] + wc[3];
}

__global__ __launch_bounds__(256) void scan256(const int* __restrict__ cnt,
                                               int* __restrict__ offs) {
    __shared__ int s[256];
    int t = threadIdx.x;
    s[t] = cnt[t];
    __syncthreads();
    for (int d = 1; d < 256; d <<= 1) {
        int v = (t >= d) ? s[t - d] : 0;
        __syncthreads();
        s[t] += v;
        __syncthreads();
    }
    offs[t] = s[t] - cnt[t];
    if (t == 255) offs[256] = s[255];
}

__global__ __launch_bounds__(256) void fill_perm(const float* __restrict__ obs,
                                                 const int* __restrict__ offs,
                                                 int* __restrict__ pb,
                                                 int* __restrict__ pc) {
    int t = threadIdx.x, bid = blockIdx.x;
    int row = bid * 256 + t;
    int tag = row_tag(obs, row);
    unsigned long long m = __ballot(tag);
    __shared__ int wc[4];
    int lane = t & 63, wv = t >> 6;
    if (lane == 0) wc[wv] = __popcll(m);
    __syncthreads();
    int woff = 0;
    for (int i = 0; i < 4; ++i) if (i < wv) woff += wc[i];
    int lb = woff + __popcll(m & ((1ull << lane) - 1ull));
    int base_b = offs[bid];
    if (tag) pb[base_b + lb] = row;
    else     pc[bid * 256 - base_b + (t - lb)] = row;
}

// LDS map (dynamic, 154112 B, 1 block/CU). R17 = R16 (335 us) with the tail
// split 4-ways by column-quarter: grid 1028; obs 1024..1027 (dispatched LAST)
// each compute p-tile 511 x one 128-col quarter on a 2-interval loop.
// Full-path barriers (R14): B1 v(2) | B2 v(0) | B3 v(0) | B4 v(4) | B5 v(2)
// Quarter-tail barriers:    B1 v(2) | B2 v(0)
//   (I1: stage q(hc+1)->pong (2), GEMM1, H | I2: hA, stage W1'(4), MFMA q(cur).
//    B1: hc=0 retires prologue q0, else no-wait; B2 v(0) retires q'+W1'.
//    WAR: pong staged I1 was read prev I2 (sep B2); W1' staged I2 after
//    GEMM1's last W1 read (sep B1); H w(I1) r(I2) sep B1 lgkm.)
//   ldsX   @ 0      [128][256] bf16 = 64K  persistent, swz (r&7)<<4
//   ldsW1  @ 65536  [64][256]  bf16 = 32K  single-buffered W1 chunk
//   ldsQA  @ 98304  [128][64]  bf16 = 16K  W2 quarter ping
//   ldsQB  @ 114688 [128][64]  bf16 = 16K  W2 quarter pong
//   ldsH   @ 131072 [128][64]  bf16 = 16K
//   ldsB1  @ 147456 float[1024]
//   ldsB2  @ 151552 float[512]
//   ldsPr  @ 153600 int[128]
__global__ __launch_bounds__(512, 2) void fused_mlp(
    const float* __restrict__ obs,
    const unsigned short* __restrict__ wts,
    const int* __restrict__ perm_b, const int* __restrict__ perm_c,
    const int* __restrict__ offs,
    const float* __restrict__ b1_0, const float* __restrict__ b2_0,
    const float* __restrict__ b1_1, const float* __restrict__ b2_1,
    const float* __restrict__ b1_2, const float* __restrict__ b2_2,
    float* __restrict__ out)
{
    extern __shared__ char lds[];
    char* ldsX  = lds;
    char* ldsW1 = lds + 65536;
    char* ldsQA = lds + 98304;
    char* ldsQB = lds + 114688;
    char* ldsH  = lds + 131072;
    float* ldsB1 = (float*)(lds + 147456);
    float* ldsB2 = (float*)(lds + 151552);
    int*  ldsPr  = (int*)(lds + 153600);

    const int ob = blockIdx.x;
    int branch, base, cnt, qtail = -1;
    const int* perm;
    if (ob >= 1024) {
        // tail quartet: column-quarters of p-tile 511 (run in round 5)
        qtail = ob - 1024;            // quarter index 0..3 (cols q*128..+127)
        branch = 2; base = 511 * 128; cnt = NROWS; perm = nullptr;
    } else {
        // bijective XCD swizzle over 1024 = 8*128: XCD gets contiguous wids
        const int wid = (ob & 7) * 128 + (ob >> 3);
        if (wid < 511) {
            branch = 2; base = wid * 128; cnt = NROWS; perm = nullptr;
        } else {
            int eb = wid - 511;       // 0..512 -> 513 expert slots
            int nb = offs[256];
            int nbb = (nb + 127) >> 7;
            int nc = NROWS - nb;
            int ncb = (nc + 127) >> 7;
            if (eb < nbb)            { branch = 0; base = eb * 128;         cnt = nb; perm = perm_b; }
            else if (eb < nbb + ncb) { branch = 1; base = (eb - nbb) * 128; cnt = nc; perm = perm_c; }
            else return;
        }
    }

    const float* b1 = branch == 0 ? b1_0 : (branch == 1 ? b1_1 : b1_2);
    const float* b2 = branch == 0 ? b2_0 : (branch == 1 ? b2_1 : b2_2);
    const char* w1t = (const char*)(wts + (size_t)branch * (DH * DIN));
    const char* w2t = (const char*)(wts + (size_t)3 * DH * DIN + (size_t)branch * (DF * DH));

    const int t = threadIdx.x;
    const int lane = t & 63;
    const int w = t >> 6;
    const int l15 = lane & 15;
    const int g = lane >> 4;

    // ---- prologue: tables + X staging (all non-gll16 VMEM lives here)
    ldsB1[t] = b1[t];
    ldsB1[t + 512] = b1[t + 512];
    ldsB2[t] = b2[t];
    if (t < 128) {
        int gr = base + t;
        ldsPr[t] = (gr < cnt) ? (perm ? perm[gr] : gr) : -1;
    }
    #pragma unroll
    for (int i = 0; i < 16; ++i) {
        int idx = t + i * 512;
        int r = idx >> 6, c4 = idx & 63;
        int gr = base + r;
        int grow = gr < cnt ? gr : cnt - 1;
        if (perm) grow = perm[grow];
        f32x4 v = *(const f32x4*)(obs + (size_t)grow * DIN + c4 * 4);
        ushort4 p4;
        p4.x = f2b(v.x); p4.y = f2b(v.y); p4.z = f2b(v.z); p4.w = f2b(v.w);
        *(ushort4*)(ldsX + r * 512 + ((c4 * 8) ^ ((r & 7) << 4))) = p4;
    }
    DRAIN_VM();   // force-drain obs/table loads so loop vmcnt counts are exact

    #define STAGE_Q(buf, q, hc_)                                               \
        {                                                                      \
            _Pragma("unroll")                                                  \
            for (int i = 0; i < 2; ++i) {                                      \
                int slot = t + i * 512;                                        \
                int nl = slot >> 3, boff = (slot & 7) << 4;                    \
                gll16(w2t + (size_t)((q) * 128 + nl) * 2048 + (hc_) * 128      \
                          + (boff ^ ((nl & 7) << 4)),                          \
                      (buf) + slot * 16);                                      \
            }                                                                  \
        }

    #define STAGE_W1(hc_)                                                      \
        {                                                                      \
            _Pragma("unroll")                                                  \
            for (int i = 0; i < 4; ++i) {                                      \
                int slot = t + i * 512;                                        \
                int nl = slot >> 5, boff = (slot & 31) << 4;                   \
                gll16(w1t + (size_t)((hc_) * 64 + nl) * 512 + (boff ^ ((nl & 7) << 4)), \
                      ldsW1 + slot * 16);                                      \
            }                                                                  \
        }

    // wave roles
    const int rg = w & 3, cg = w >> 2;   // GEMM1: rows rg*32, hcols cg*32
    const int wr = w >> 2, wc = w & 3;   // GEMM2: rows wr*64, fcols wc*32/quarter

    const int ar0 = rg * 32 + l15, ar1 = ar0 + 16;
    const int asw0 = (ar0 & 7) << 4, asw1 = (ar1 & 7) << 4;
    const int bn0 = cg * 32 + l15, bn1 = bn0 + 16;
    const int bsw0 = (bn0 & 7) << 4, bsw1 = (bn1 & 7) << 4;

    #define GEMM1_BODY(hc_)                                                    \
        f32x4 aH[2][2];                                                        \
        _Pragma("unroll")                                                      \
        for (int a = 0; a < 2; ++a)                                            \
            _Pragma("unroll")                                                  \
            for (int b = 0; b < 2; ++b)                                        \
                _Pragma("unroll")                                              \
                for (int e = 0; e < 4; ++e) aH[a][b][e] = 0.0f;                \
        __builtin_amdgcn_s_setprio(1);                                         \
        _Pragma("unroll")                                                      \
        for (int kk = 0; kk < 8; ++kk) {                                       \
            int kb = kk * 64 + g * 16;                                         \
            bf16x8 a0 = *(const bf16x8*)(ldsX  + ar0 * 512 + (kb ^ asw0));     \
            bf16x8 a1 = *(const bf16x8*)(ldsX  + ar1 * 512 + (kb ^ asw1));     \
            bf16x8 b0 = *(const bf16x8*)(ldsW1 + bn0 * 512 + (kb ^ bsw0));     \
            bf16x8 b1f = *(const bf16x8*)(ldsW1 + bn1 * 512 + (kb ^ bsw1));    \
            aH[0][0] = __builtin_amdgcn_mfma_f32_16x16x32_bf16(a0, b0,  aH[0][0], 0, 0, 0); \
            aH[0][1] = __builtin_amdgcn_mfma_f32_16x16x32_bf16(a0, b1f, aH[0][1], 0, 0, 0); \
            aH[1][0] = __builtin_amdgcn_mfma_f32_16x16x32_bf16(a1, b0,  aH[1][0], 0, 0, 0); \
            aH[1][1] = __builtin_amdgcn_mfma_f32_16x16x32_bf16(a1, b1f, aH[1][1], 0, 0, 0); \
        }                                                                      \
        __builtin_amdgcn_s_setprio(0);                                         \
        {                                                                      \
            float b1v0 = ldsB1[(hc_) * 64 + cg * 32 + l15];                    \
            float b1v1 = ldsB1[(hc_) * 64 + cg * 32 + 16 + l15];               \
            _Pragma("unroll")                                                  \
            for (int art = 0; art < 2; ++art)                                  \
                _Pragma("unroll")                                              \
                for (int bct = 0; bct < 2; ++bct) {                            \
                    int col2 = (cg * 32 + bct * 16 + l15) * 2;                 \
                    float bv = bct ? b1v1 : b1v0;                              \
                    _Pragma("unroll")                                          \
                    for (int r = 0; r < 4; ++r) {                              \
                        int hrow = rg * 32 + art * 16 + g * 4 + r;             \
                        float vv = fmaxf(aH[art][bct][r] + bv, 0.0f);          \
                        *(unsigned short*)(ldsH + hrow * 128 + (col2 ^ ((hrow & 7) << 4))) = f2b(vv); \
                    }                                                          \
                }                                                              \
        }

    #define LOAD_HA()                                                          \
        bf16x8 hA[4][2];                                                       \
        _Pragma("unroll")                                                      \
        for (int rt = 0; rt < 4; ++rt)                                         \
            _Pragma("unroll")                                                  \
            for (int k2 = 0; k2 < 2; ++k2) {                                   \
                int hr = wr * 64 + rt * 16 + l15;                              \
                hA[rt][k2] = *(const bf16x8*)(ldsH + hr * 128 + ((k2 * 64 + g * 16) ^ ((hr & 7) << 4))); \
            }

    if (qtail < 0) {
        // =================== FULL path (R14 engine, unchanged) ===============
        f32x4 acc[4][8];
        #pragma unroll
        for (int a = 0; a < 4; ++a)
            #pragma unroll
            for (int b = 0; b < 8; ++b)
                #pragma unroll
                for (int e = 0; e < 4; ++e) acc[a][b][e] = 0.0f;

        #define QUARTER_MFMA(buf, c0)                                          \
            {                                                                  \
                _Pragma("unroll")                                              \
                for (int k2 = 0; k2 < 2; ++k2)                                 \
                    _Pragma("unroll")                                          \
                    for (int ct = 0; ct < 2; ++ct) {                           \
                        int fr = wc * 32 + ct * 16 + l15;                      \
                        bf16x8 bb = *(const bf16x8*)((buf) + fr * 128 +        \
                                     ((k2 * 64 + g * 16) ^ ((fr & 7) << 4)));  \
                        _Pragma("unroll")                                      \
                        for (int rt = 0; rt < 4; ++rt)                         \
                            acc[rt][(c0) + ct] = __builtin_amdgcn_mfma_f32_16x16x32_bf16( \
                                hA[rt][k2], bb, acc[rt][(c0) + ct], 0, 0, 0);  \
                    }                                                          \
            }

        STAGE_W1(0);
        STAGE_Q(ldsQA, 0, 0);
        BAR_V(2);   // retire W1[0]; q0 stays in flight

        for (int hc = 0; hc < 16; ++hc) {
            // I1: stage q1->QB ; GEMM1 + bias/relu -> H
            STAGE_Q(ldsQB, 1, hc);
            GEMM1_BODY(hc);
            BAR_V(2);   // B1: retire q0 (keep q1); H visible

            // I2: hA loads ; GEMM2 q0 (QA)
            LOAD_HA();
            __builtin_amdgcn_s_setprio(1);
            QUARTER_MFMA(ldsQA, 0);
            __builtin_amdgcn_s_setprio(0);
            BAR_V(0);   // B2: retire q1 (2-interval lead)

            // I3: stage q2->QA ; GEMM2 q1 (QB)
            STAGE_Q(ldsQA, 2, hc);
            __builtin_amdgcn_s_setprio(1);
            QUARTER_MFMA(ldsQB, 2);
            __builtin_amdgcn_s_setprio(0);
            BAR_V(0);   // B3: retire q2

            // I4: stage q3->QB ; stage W1[hc+1] ; GEMM2 q2 (QA)
            STAGE_Q(ldsQB, 3, hc);
            STAGE_W1((hc + 1) & 15);
            __builtin_amdgcn_s_setprio(1);
            QUARTER_MFMA(ldsQA, 4);
            __builtin_amdgcn_s_setprio(0);
            BAR_V(4);   // B4: retire q3 (keep W1')

            // I5: stage next q0->QA ; GEMM2 q3 (QB)
            STAGE_Q(ldsQA, 0, (hc + 1) & 15);
            __builtin_amdgcn_s_setprio(1);
            QUARTER_MFMA(ldsQB, 6);
            __builtin_amdgcn_s_setprio(0);
            BAR_V(2);   // B5: retire W1' (keep next q0)
        }
        DRAIN_VM();

        // epilogue: bias2 + permuted scatter store
        int colq[8]; float b2v[8];
        #pragma unroll
        for (int q = 0; q < 8; ++q) {
            colq[q] = (q >> 1) * 128 + wc * 32 + (q & 1) * 16 + l15;
            b2v[q] = ldsB2[colq[q]];
        }
        const int cb = (branch == 2) ? DF : 0;
        #pragma unroll
        for (int rt = 0; rt < 4; ++rt)
            #pragma unroll
            for (int r = 0; r < 4; ++r) {
                int row = wr * 64 + rt * 16 + g * 4 + r;
                int prow = ldsPr[row];
                if (prow >= 0) {
                    float* op = out + (size_t)prow * (2 * DF) + cb;
                    #pragma unroll
                    for (int q = 0; q < 8; ++q)
                        op[colq[q]] = acc[rt][q][r] + b2v[q];
                }
            }
    } else {
        // ============= QUARTER-tail path (4 blocks, 2 intervals) =============
        f32x4 acc2[4][2];
        #pragma unroll
        for (int a = 0; a < 4; ++a)
            #pragma unroll
            for (int b = 0; b < 2; ++b)
                #pragma unroll
                for (int e = 0; e < 4; ++e) acc2[a][b][e] = 0.0f;

        STAGE_W1(0);
        STAGE_Q(ldsQA, qtail, 0);
        BAR_V(2);   // retire W1[0]; q(0) stays in flight

        for (int hc = 0; hc < 16; ++hc) {
            char* curQ = (hc & 1) ? ldsQB : ldsQA;
            char* nxtQ = (hc & 1) ? ldsQA : ldsQB;
            // I1: stage q(hc+1)->nxtQ ; GEMM1 + bias/relu -> H
            STAGE_Q(nxtQ, qtail, (hc + 1) & 15);
            GEMM1_BODY(hc);
            BAR_V(2);   // B1: hc=0 retires q(0); else no-wait. H visible.

            // I2: hA ; stage W1(hc+1) ; MFMA q(hc) from curQ
            LOAD_HA();
            STAGE_W1((hc + 1) & 15);
            __builtin_amdgcn_s_setprio(1);
            #pragma unroll
            for (int k2 = 0; k2 < 2; ++k2)
                #pragma unroll
                for (int ct = 0; ct < 2; ++ct) {
                    int fr = wc * 32 + ct * 16 + l15;
                    bf16x8 bb = *(const bf16x8*)(curQ + fr * 128 +
                                 ((k2 * 64 + g * 16) ^ ((fr & 7) << 4)));
                    #pragma unroll
                    for (int rt = 0; rt < 4; ++rt)
                        acc2[rt][ct] = __builtin_amdgcn_mfma_f32_16x16x32_bf16(
                            hA[rt][k2], bb, acc2[rt][ct], 0, 0, 0);
                }
            __builtin_amdgcn_s_setprio(0);
            BAR_V(0);   // B2: retire q(hc+1) + W1(hc+1) (both needed next I1/I2)
        }
        DRAIN_VM();

        // epilogue: cols DF + qtail*128 + (wc*32 + ct*16 + l15); branch p rows
        int colq2[2]; float b2v2[2];
        #pragma unroll
        for (int c = 0; c < 2; ++c) {
            colq2[c] = wc * 32 + c * 16 + l15;
            b2v2[c] = ldsB2[qtail * 128 + colq2[c]];
        }
        const int cb = DF + qtail * 128;
        #pragma unroll
        for (int rt = 0; rt < 4; ++rt)
            #pragma unroll
            for (int r = 0; r < 4; ++r) {
                int row = wr * 64 + rt * 16 + g * 4 + r;
                int prow = ldsPr[row];
                if (prow >= 0) {
                    float* op = out + (size_t)prow * (2 * DF) + cb;
                    op[colq2[0]] = acc2[rt][0][r] + b2v2[0];
                    op[colq2[1]] = acc2[rt][1][r] + b2v2[1];
                }
            }
    }
}

extern "C" void kernel_launch(void* const* d_in, const int* in_sizes, int n_in,
                              void* d_out, int out_size, void* d_ws, size_t ws_size,
                              hipStream_t stream) {
    const float* obs = (const float*)d_in[0];
    const float* W1[3] = {(const float*)d_in[1], (const float*)d_in[5], (const float*)d_in[9]};
    const float* b1[3] = {(const float*)d_in[2], (const float*)d_in[6], (const float*)d_in[10]};
    const float* W2[3] = {(const float*)d_in[3], (const float*)d_in[7], (const float*)d_in[11]};
    const float* b2[3] = {(const float*)d_in[4], (const float*)d_in[8], (const float*)d_in[12]};

    char* ws = (char*)d_ws;
    unsigned short* wts = (unsigned short*)(ws + WS_WTS);
    int* pb   = (int*)(ws + WS_PB);
    int* pc   = (int*)(ws + WS_PC);
    int* cnt  = (int*)(ws + WS_CNT);
    int* offs = (int*)(ws + WS_OFFS);

    for (int br = 0; br < 3; ++br) {
        transpose_to_bf16<<<dim3(DIN / 64, DH / 64), 256, 0, stream>>>(
            W1[br], wts + (size_t)br * DH * DIN, DIN, DH);
        transpose_to_bf16<<<dim3(DH / 64, DF / 64), 256, 0, stream>>>(
            W2[br], wts + (size_t)3 * DH * DIN + (size_t)br * DF * DH, DH, DF);
    }
    tag_count<<<256, 256, 0, stream>>>(obs, cnt);
    scan256<<<1, 256, 0, stream>>>(cnt, offs);
    fill_perm<<<256, 256, 0, stream>>>(obs, offs, pb, pc);

    hipFuncSetAttribute((const void*)fused_mlp,
                        hipFuncAttributeMaxDynamicSharedMemorySize, 154112);
    fused_mlp<<<1028, 512, 154112, stream>>>(obs, wts, pb, pc, offs,
        b1[0], b2[0], b1[1], b2[1], b1[2], b2[2], (float*)d_out);
}